// Round 1
// baseline (4256.804 us; speedup 1.0000x reference)
//
#include <hip/hip_runtime.h>

#define LATENT 32
#define NN     100000
#define E1N    3200000
#define N2N    200000
#define E2N    3200000
#define MN     131072
#define EPSV   1e-5f

#define SCAN_CHUNK 2048

// ---------------- workspace layout (bytes) ----------------
constexpr size_t OFF_HA    = 0;
constexpr size_t OFF_HB    = OFF_HA    + (size_t)N2N * 32 * 4;   // 25.6 MB each
constexpr size_t OFF_CSRA  = OFF_HB    + (size_t)N2N * 32 * 4;   // 12.8 MB (csr1 then csr2)
constexpr size_t OFF_CSRB  = OFF_CSRA  + (size_t)E2N * 4;        // 12.8 MB (csr2r)
constexpr size_t OFF_OFF1  = OFF_CSRB  + (size_t)E2N * 4;        // (NN+1) ints
constexpr size_t OFF_OFF2  = OFF_OFF1  + 401408;                 // (N2N+1) ints
constexpr size_t OFF_OFF2R = OFF_OFF2  + 801280;
constexpr size_t OFF_CUR   = OFF_OFF2R + 801280;                 // N2N ints
constexpr size_t OFF_BSUM  = OFF_CUR   + 800000;
constexpr size_t OFF_STATS = OFF_BSUM  + 1024;
constexpr size_t OFF_AFF   = OFF_STATS + 256;

// ---------------- kernels ----------------

__global__ void k_embed_stats(const int* __restrict__ x, const float* __restrict__ emb,
                              float* __restrict__ h, float* __restrict__ stats, int n) {
    __shared__ float lsum[256], lsq[256];
    int tid = threadIdx.x;
    float s = 0.f, q = 0.f;
    int stride = gridDim.x * blockDim.x;
    for (int idx = blockIdx.x * blockDim.x + tid; idx < n * 32; idx += stride) {
        int i = idx >> 5, k = idx & 31;
        float v = emb[x[i] * 32 + k];
        h[idx] = v;
        s += v; q += v * v;
    }
    lsum[tid] = s; lsq[tid] = q;
    __syncthreads();
    if (tid < 32) {
        float ts = 0.f, tq = 0.f;
        #pragma unroll
        for (int r = 0; r < 8; ++r) { ts += lsum[tid + r * 32]; tq += lsq[tid + r * 32]; }
        atomicAdd(&stats[tid], ts);
        atomicAdd(&stats[32 + tid], tq);
    }
}

__global__ void k_affine(const float* __restrict__ stats, const float* __restrict__ w,
                         const float* __restrict__ b, const float* __restrict__ ms,
                         float* __restrict__ aff, int n) {
    int k = threadIdx.x;
    if (k < 32) {
        float mean = stats[k] / (float)n;
        float m2   = stats[32 + k] / (float)n;
        float m    = ms[k];
        float var  = m2 - 2.f * m * mean * mean + m * m * mean * mean;
        float A    = w[k] / sqrtf(var + EPSV);
        aff[k]      = A;
        aff[32 + k] = b[k] - A * m * mean;
    }
}

__global__ void k_apply_affine(float* __restrict__ h, const float* __restrict__ aff, int total) {
    int idx = blockIdx.x * blockDim.x + threadIdx.x;
    int stride = gridDim.x * blockDim.x;
    for (; idx < total; idx += stride) {
        int k = idx & 31;
        h[idx] = h[idx] * aff[k] + aff[32 + k];
    }
}

__global__ void k_count(const int* __restrict__ dst, int* __restrict__ off, int ne) {
    int idx = blockIdx.x * blockDim.x + threadIdx.x;
    int stride = gridDim.x * blockDim.x;
    for (; idx < ne; idx += stride) atomicAdd(&off[dst[idx] + 1], 1);
}

__global__ void k_scan_partial(const int* __restrict__ off, int* __restrict__ bsum, int n) {
    __shared__ int lds[256];
    int t = threadIdx.x;
    int base = blockIdx.x * SCAN_CHUNK + t * 8;
    int s = 0;
    #pragma unroll
    for (int j = 0; j < 8; ++j) { int e = base + j; if (e < n) s += off[e + 1]; }
    lds[t] = s; __syncthreads();
    for (int o = 128; o > 0; o >>= 1) { if (t < o) lds[t] += lds[t + o]; __syncthreads(); }
    if (t == 0) bsum[blockIdx.x] = lds[0];
}

__global__ void k_scan_bsum(int* __restrict__ bsum, int nb) {
    if (threadIdx.x == 0 && blockIdx.x == 0) {
        int run = 0;
        for (int j = 0; j < nb; ++j) { int t = bsum[j]; bsum[j] = run; run += t; }
    }
}

__global__ void k_scan_final(int* __restrict__ off, int* __restrict__ cur,
                             const int* __restrict__ bsum, int n) {
    __shared__ int lds[256];
    int t = threadIdx.x;
    int base = blockIdx.x * SCAN_CHUNK + t * 8;
    int v[8]; int run = 0;
    #pragma unroll
    for (int j = 0; j < 8; ++j) {
        int e = base + j;
        v[j] = (e < n) ? off[e + 1] : 0;
        run += v[j];
    }
    int tot = run;
    lds[t] = tot; __syncthreads();
    for (int o = 1; o < 256; o <<= 1) {
        int add = (t >= o) ? lds[t - o] : 0;
        __syncthreads();
        lds[t] += add;
        __syncthreads();
    }
    int excl = lds[t] - tot + bsum[blockIdx.x];
    int run2 = excl;
    #pragma unroll
    for (int j = 0; j < 8; ++j) {
        int e = base + j;
        if (e < n) {
            run2 += v[j];
            off[e + 1] = run2;      // inclusive scan -> off[v] = start of v
            cur[e]     = run2 - v[j];
        }
    }
}

__global__ void k_fill(const int* __restrict__ src, const int* __restrict__ dst,
                       int* __restrict__ cur, int* __restrict__ csr, int ne) {
    int idx = blockIdx.x * blockDim.x + threadIdx.x;
    int stride = gridDim.x * blockDim.x;
    for (; idx < ne; idx += stride) {
        int p = atomicAdd(&cur[dst[idx]], 1);
        csr[p] = src[idx];
    }
}

// one 32-lane group per node; lane = feature
__global__ void __launch_bounds__(256) k_sage(
    const float* __restrict__ hin, float* __restrict__ hout,
    const int* __restrict__ csr, const int* __restrict__ off,
    const float* __restrict__ wl, const float* __restrict__ bl, const float* __restrict__ wr,
    int n) {
    __shared__ float wlT[32][33];
    __shared__ float wrT[32][33];
    int tid = threadIdx.x;
    for (int idx = tid; idx < 1024; idx += 256) {
        int j = idx >> 5, k = idx & 31;
        wlT[k][j] = wl[idx];
        wrT[k][j] = wr[idx];
    }
    __syncthreads();
    int lane  = tid & 31;
    int node  = blockIdx.x * 8 + (tid >> 5);
    int gstep = gridDim.x * 8;
    for (; node < n; node += gstep) {
        int s0 = off[node], s1 = off[node + 1];
        float s = 0.f;
        for (int e = s0; e < s1; ++e) {
            int src = csr[e];
            s += hin[src * 32 + lane];
        }
        int c = s1 - s0;
        s *= 1.0f / (float)(c > 0 ? c : 1);
        float hr  = hin[node * 32 + lane];
        float acc = bl[lane];
        #pragma unroll
        for (int k = 0; k < 32; ++k) {
            float sk = __shfl(s, k, 32);
            float hk = __shfl(hr, k, 32);
            acc = fmaf(sk, wlT[k][lane], acc);
            acc = fmaf(hk, wrT[k][lane], acc);
        }
        hout[node * 32 + lane] = fmaxf(acc, 0.f);
    }
}

// fused dual-direction sage: relu(sageF) + relu(sageR)
__global__ void __launch_bounds__(256) k_sage2(
    const float* __restrict__ hin, float* __restrict__ hout,
    const int* __restrict__ csrF, const int* __restrict__ offF,
    const int* __restrict__ csrR, const int* __restrict__ offR,
    const float* __restrict__ wlF, const float* __restrict__ blF, const float* __restrict__ wrF,
    const float* __restrict__ wlR, const float* __restrict__ blR, const float* __restrict__ wrR,
    int n) {
    __shared__ float WLF[32][33], WRF[32][33], WLR[32][33], WRR[32][33];
    int tid = threadIdx.x;
    for (int idx = tid; idx < 1024; idx += 256) {
        int j = idx >> 5, k = idx & 31;
        WLF[k][j] = wlF[idx];
        WRF[k][j] = wrF[idx];
        WLR[k][j] = wlR[idx];
        WRR[k][j] = wrR[idx];
    }
    __syncthreads();
    int lane  = tid & 31;
    int node  = blockIdx.x * 8 + (tid >> 5);
    int gstep = gridDim.x * 8;
    for (; node < n; node += gstep) {
        int f0 = offF[node], f1 = offF[node + 1];
        float sf = 0.f;
        for (int e = f0; e < f1; ++e) sf += hin[csrF[e] * 32 + lane];
        int cf = f1 - f0;
        sf *= 1.0f / (float)(cf > 0 ? cf : 1);

        int r0 = offR[node], r1 = offR[node + 1];
        float sr = 0.f;
        for (int e = r0; e < r1; ++e) sr += hin[csrR[e] * 32 + lane];
        int cr = r1 - r0;
        sr *= 1.0f / (float)(cr > 0 ? cr : 1);

        float hr   = hin[node * 32 + lane];
        float accF = blF[lane];
        float accR = blR[lane];
        #pragma unroll
        for (int k = 0; k < 32; ++k) {
            float sfk = __shfl(sf, k, 32);
            float srk = __shfl(sr, k, 32);
            float hk  = __shfl(hr, k, 32);
            accF = fmaf(sfk, WLF[k][lane], accF);
            accF = fmaf(hk,  WRF[k][lane], accF);
            accR = fmaf(srk, WLR[k][lane], accR);
            accR = fmaf(hk,  WRR[k][lane], accR);
        }
        hout[node * 32 + lane] = fmaxf(accF, 0.f) + fmaxf(accR, 0.f);
    }
}

__global__ void k_pair(const float* __restrict__ h, const int* __restrict__ pos1,
                       float* __restrict__ hp, int total) {
    int idx = blockIdx.x * blockDim.x + threadIdx.x;
    int stride = gridDim.x * blockDim.x;
    for (; idx < total; idx += stride) {
        int r = idx >> 5, k = idx & 31;
        int a = pos1[2 * r], b = pos1[2 * r + 1];
        hp[idx] = h[a * 32 + k] * h[b * 32 + k];
    }
}

__global__ void k_final(const float* __restrict__ h, const int* __restrict__ pos2,
                        const float* __restrict__ pw, const float* __restrict__ pb,
                        float* __restrict__ out, int m2) {
    int tid  = threadIdx.x;
    int lane = tid & 31;
    int i    = blockIdx.x * 8 + (tid >> 5);
    if (i >= m2) return;
    int p0 = pos2[2 * i], p1 = pos2[2 * i + 1];
    float v = h[p0 * 32 + lane] * h[p1 * 32 + lane] * pw[lane];
    #pragma unroll
    for (int o = 16; o > 0; o >>= 1) v += __shfl_xor(v, o, 32);
    if (lane == 0) out[i] = v + pb[0];
}

// ---------------- launch ----------------

extern "C" void kernel_launch(void* const* d_in, const int* in_sizes, int n_in,
                              void* d_out, int out_size, void* d_ws, size_t ws_size,
                              hipStream_t stream) {
    const int*   x      = (const int*)d_in[0];
    const int*   edge1  = (const int*)d_in[2];
    const int*   edge2  = (const int*)d_in[3];
    const int*   edge2r = (const int*)d_in[4];
    const int*   pos1   = (const int*)d_in[5];
    const int*   pos2   = (const int*)d_in[6];
    const float* emb    = (const float*)d_in[7];
    const float* gw     = (const float*)d_in[8];
    const float* gb     = (const float*)d_in[9];
    const float* gms    = (const float*)d_in[10];
    const float* c1wl   = (const float*)d_in[11];
    const float* c1bl   = (const float*)d_in[12];
    const float* c1wr   = (const float*)d_in[13];
    const float* c2wl   = (const float*)d_in[14];
    const float* c2bl   = (const float*)d_in[15];
    const float* c2wr   = (const float*)d_in[16];
    const float* c2rwl  = (const float*)d_in[17];
    const float* c2rbl  = (const float*)d_in[18];
    const float* c2rwr  = (const float*)d_in[19];
    const float* pw     = (const float*)d_in[20];
    const float* pb     = (const float*)d_in[21];
    float* out = (float*)d_out;

    char* ws = (char*)d_ws;
    float* hA    = (float*)(ws + OFF_HA);
    float* hB    = (float*)(ws + OFF_HB);
    int*   csrA  = (int*)(ws + OFF_CSRA);
    int*   csrB  = (int*)(ws + OFF_CSRB);
    int*   off1  = (int*)(ws + OFF_OFF1);
    int*   off2  = (int*)(ws + OFF_OFF2);
    int*   off2r = (int*)(ws + OFF_OFF2R);
    int*   cur   = (int*)(ws + OFF_CUR);
    int*   bsum  = (int*)(ws + OFF_BSUM);
    float* stats = (float*)(ws + OFF_STATS);
    float* aff   = (float*)(ws + OFF_AFF);

    hipMemsetAsync(stats, 0, 256, stream);
    hipMemsetAsync(off1, 0, (NN + 1) * sizeof(int), stream);
    hipMemsetAsync(off2, 0, (N2N + 1) * sizeof(int), stream);
    hipMemsetAsync(off2r, 0, (N2N + 1) * sizeof(int), stream);

    // embedding + GraphNorm
    k_embed_stats<<<1024, 256, 0, stream>>>(x, emb, hA, stats, NN);
    k_affine<<<1, 64, 0, stream>>>(stats, gw, gb, gms, aff, NN);
    k_apply_affine<<<2048, 256, 0, stream>>>(hA, aff, NN * 32);

    // CSR for edge1 (into csrA)
    int nb1 = (NN + SCAN_CHUNK - 1) / SCAN_CHUNK;
    k_count<<<2048, 256, 0, stream>>>(edge1 + E1N, off1, E1N);
    k_scan_partial<<<nb1, 256, 0, stream>>>(off1, bsum, NN);
    k_scan_bsum<<<1, 1, 0, stream>>>(bsum, nb1);
    k_scan_final<<<nb1, 256, 0, stream>>>(off1, cur, bsum, NN);
    k_fill<<<2048, 256, 0, stream>>>(edge1, edge1 + E1N, cur, csrA, E1N);

    // conv1: hA -> hB -> hA
    k_sage<<<(NN + 7) / 8, 256, 0, stream>>>(hA, hB, csrA, off1, c1wl, c1bl, c1wr, NN);
    k_sage<<<(NN + 7) / 8, 256, 0, stream>>>(hB, hA, csrA, off1,
                                             c1wl + 1024, c1bl + 32, c1wr + 1024, NN);

    // pair features: hA (N rows) -> hB (N2 rows)
    k_pair<<<2048, 256, 0, stream>>>(hA, pos1, hB, N2N * 32);

    // CSR for edge2 (into csrA, overwriting csr1) and edge2_r (into csrB)
    int nb2 = (N2N + SCAN_CHUNK - 1) / SCAN_CHUNK;
    k_count<<<2048, 256, 0, stream>>>(edge2 + E2N, off2, E2N);
    k_scan_partial<<<nb2, 256, 0, stream>>>(off2, bsum, N2N);
    k_scan_bsum<<<1, 1, 0, stream>>>(bsum, nb2);
    k_scan_final<<<nb2, 256, 0, stream>>>(off2, cur, bsum, N2N);
    k_fill<<<2048, 256, 0, stream>>>(edge2, edge2 + E2N, cur, csrA, E2N);

    k_count<<<2048, 256, 0, stream>>>(edge2r + E2N, off2r, E2N);
    k_scan_partial<<<nb2, 256, 0, stream>>>(off2r, bsum, N2N);
    k_scan_bsum<<<1, 1, 0, stream>>>(bsum, nb2);
    k_scan_final<<<nb2, 256, 0, stream>>>(off2r, cur, bsum, N2N);
    k_fill<<<2048, 256, 0, stream>>>(edge2r, edge2r + E2N, cur, csrB, E2N);

    // conv2: hB -> hA -> hB  (fused forward+reverse each layer)
    k_sage2<<<(N2N + 7) / 8, 256, 0, stream>>>(hB, hA, csrA, off2, csrB, off2r,
        c2wl, c2bl, c2wr, c2rwl, c2rbl, c2rwr, N2N);
    k_sage2<<<(N2N + 7) / 8, 256, 0, stream>>>(hA, hB, csrA, off2, csrB, off2r,
        c2wl + 1024, c2bl + 32, c2wr + 1024, c2rwl + 1024, c2rbl + 32, c2rwr + 1024, N2N);

    // head: gather pos2, even*odd, dot with pred_w
    k_final<<<(MN / 2) / 8, 256, 0, stream>>>(hB, pos2, pw, pb, out, MN / 2);
}

// Round 2
// 2650.322 us; speedup vs baseline: 1.6061x; 1.6061x over previous
//
#include <hip/hip_runtime.h>

#define LATENT 32
#define NN     100000
#define E1N    3200000
#define N2N    200000
#define E2N    3200000
#define MN     131072
#define EPSV   1e-5f

#define SCAN_CHUNK 2048

// ---------------- workspace layout (bytes) ----------------
constexpr size_t OFF_HA    = 0;
constexpr size_t OFF_HB    = OFF_HA    + (size_t)N2N * 32 * 4;   // 25.6 MB each
constexpr size_t OFF_CSRA  = OFF_HB    + (size_t)N2N * 32 * 4;   // 12.8 MB (csr1 then csr2)
constexpr size_t OFF_CSRB  = OFF_CSRA  + (size_t)E2N * 4;        // 12.8 MB (csr2r)
constexpr size_t OFF_OFF1  = OFF_CSRB  + (size_t)E2N * 4;        // (NN+1) ints
constexpr size_t OFF_OFF2  = OFF_OFF1  + 401408;                 // (N2N+1) ints
constexpr size_t OFF_OFF2R = OFF_OFF2  + 801280;
constexpr size_t OFF_CUR   = OFF_OFF2R + 801280;                 // N2N ints
constexpr size_t OFF_BSUM  = OFF_CUR   + 800000;
constexpr size_t OFF_STATS = OFF_BSUM  + 1024;
constexpr size_t OFF_AFF   = OFF_STATS + 256;

// ---------------- kernels ----------------

__global__ void k_embed_stats(const int* __restrict__ x, const float* __restrict__ emb,
                              float* __restrict__ h, float* __restrict__ stats, int n) {
    __shared__ float lsum[256], lsq[256];
    int tid = threadIdx.x;
    float s = 0.f, q = 0.f;
    int stride = gridDim.x * blockDim.x;
    for (int idx = blockIdx.x * blockDim.x + tid; idx < n * 32; idx += stride) {
        int i = idx >> 5, k = idx & 31;
        float v = emb[x[i] * 32 + k];
        h[idx] = v;
        s += v; q += v * v;
    }
    lsum[tid] = s; lsq[tid] = q;
    __syncthreads();
    if (tid < 32) {
        float ts = 0.f, tq = 0.f;
        #pragma unroll
        for (int r = 0; r < 8; ++r) { ts += lsum[tid + r * 32]; tq += lsq[tid + r * 32]; }
        atomicAdd(&stats[tid], ts);
        atomicAdd(&stats[32 + tid], tq);
    }
}

__global__ void k_affine(const float* __restrict__ stats, const float* __restrict__ w,
                         const float* __restrict__ b, const float* __restrict__ ms,
                         float* __restrict__ aff, int n) {
    int k = threadIdx.x;
    if (k < 32) {
        float mean = stats[k] / (float)n;
        float m2   = stats[32 + k] / (float)n;
        float m    = ms[k];
        float var  = m2 - 2.f * m * mean * mean + m * m * mean * mean;
        float A    = w[k] / sqrtf(var + EPSV);
        aff[k]      = A;
        aff[32 + k] = b[k] - A * m * mean;
    }
}

__global__ void k_apply_affine(float* __restrict__ h, const float* __restrict__ aff, int total) {
    int idx = blockIdx.x * blockDim.x + threadIdx.x;
    int stride = gridDim.x * blockDim.x;
    for (; idx < total; idx += stride) {
        int k = idx & 31;
        h[idx] = h[idx] * aff[k] + aff[32 + k];
    }
}

__global__ void k_count(const int* __restrict__ dst, int* __restrict__ off, int ne) {
    int idx = blockIdx.x * blockDim.x + threadIdx.x;
    int stride = gridDim.x * blockDim.x;
    for (; idx < ne; idx += stride) atomicAdd(&off[dst[idx] + 1], 1);
}

__global__ void k_scan_partial(const int* __restrict__ off, int* __restrict__ bsum, int n) {
    __shared__ int lds[256];
    int t = threadIdx.x;
    int base = blockIdx.x * SCAN_CHUNK + t * 8;
    int s = 0;
    #pragma unroll
    for (int j = 0; j < 8; ++j) { int e = base + j; if (e < n) s += off[e + 1]; }
    lds[t] = s; __syncthreads();
    for (int o = 128; o > 0; o >>= 1) { if (t < o) lds[t] += lds[t + o]; __syncthreads(); }
    if (t == 0) bsum[blockIdx.x] = lds[0];
}

__global__ void k_scan_bsum(int* __restrict__ bsum, int nb) {
    if (threadIdx.x == 0 && blockIdx.x == 0) {
        int run = 0;
        for (int j = 0; j < nb; ++j) { int t = bsum[j]; bsum[j] = run; run += t; }
    }
}

__global__ void k_scan_final(int* __restrict__ off, int* __restrict__ cur,
                             const int* __restrict__ bsum, int n) {
    __shared__ int lds[256];
    int t = threadIdx.x;
    int base = blockIdx.x * SCAN_CHUNK + t * 8;
    int v[8]; int run = 0;
    #pragma unroll
    for (int j = 0; j < 8; ++j) {
        int e = base + j;
        v[j] = (e < n) ? off[e + 1] : 0;
        run += v[j];
    }
    int tot = run;
    lds[t] = tot; __syncthreads();
    for (int o = 1; o < 256; o <<= 1) {
        int add = (t >= o) ? lds[t - o] : 0;
        __syncthreads();
        lds[t] += add;
        __syncthreads();
    }
    int excl = lds[t] - tot + bsum[blockIdx.x];
    int run2 = excl;
    #pragma unroll
    for (int j = 0; j < 8; ++j) {
        int e = base + j;
        if (e < n) {
            run2 += v[j];
            off[e + 1] = run2;      // inclusive scan -> off[v] = start of v
            cur[e]     = run2 - v[j];
        }
    }
}

__global__ void k_fill(const int* __restrict__ src, const int* __restrict__ dst,
                       int* __restrict__ cur, int* __restrict__ csr, int ne) {
    int idx = blockIdx.x * blockDim.x + threadIdx.x;
    int stride = gridDim.x * blockDim.x;
    for (; idx < ne; idx += stride) {
        int p = atomicAdd(&cur[dst[idx]], 1);
        csr[p] = src[idx];
    }
}

// 4-deep pipelined segment-mean gather: 4 independent gathers in flight
__device__ __forceinline__ float seg_mean(const float* __restrict__ hin,
                                          const int* __restrict__ csr,
                                          int s0, int s1, int lane) {
    float a0 = 0.f, a1 = 0.f, a2 = 0.f, a3 = 0.f;
    int e = s0;
    for (; e + 4 <= s1; e += 4) {
        int i0 = csr[e], i1 = csr[e + 1], i2 = csr[e + 2], i3 = csr[e + 3];
        float v0 = hin[i0 * 32 + lane];
        float v1 = hin[i1 * 32 + lane];
        float v2 = hin[i2 * 32 + lane];
        float v3 = hin[i3 * 32 + lane];
        a0 += v0; a1 += v1; a2 += v2; a3 += v3;
    }
    for (; e < s1; ++e) a0 += hin[csr[e] * 32 + lane];
    float s = (a0 + a1) + (a2 + a3);
    int c = s1 - s0;
    return s * (1.0f / (float)(c > 0 ? c : 1));
}

// one 32-lane group per node; lane = feature
__global__ void __launch_bounds__(256) k_sage(
    const float* __restrict__ hin, float* __restrict__ hout,
    const int* __restrict__ csr, const int* __restrict__ off,
    const float* __restrict__ wl, const float* __restrict__ bl, const float* __restrict__ wr,
    int n) {
    __shared__ float wlT[32][33];
    __shared__ float wrT[32][33];
    int tid = threadIdx.x;
    for (int idx = tid; idx < 1024; idx += 256) {
        int j = idx >> 5, k = idx & 31;
        wlT[k][j] = wl[idx];
        wrT[k][j] = wr[idx];
    }
    __syncthreads();
    int lane  = tid & 31;
    int node  = blockIdx.x * 8 + (tid >> 5);
    int gstep = gridDim.x * 8;
    for (; node < n; node += gstep) {
        float s  = seg_mean(hin, csr, off[node], off[node + 1], lane);
        float hr = hin[node * 32 + lane];
        float acc = bl[lane];
        #pragma unroll
        for (int k = 0; k < 32; ++k) {
            float sk = __shfl(s, k, 32);
            float hk = __shfl(hr, k, 32);
            acc = fmaf(sk, wlT[k][lane], acc);
            acc = fmaf(hk, wrT[k][lane], acc);
        }
        hout[node * 32 + lane] = fmaxf(acc, 0.f);
    }
}

// fused dual-direction sage: relu(sageF) + relu(sageR)
__global__ void __launch_bounds__(256) k_sage2(
    const float* __restrict__ hin, float* __restrict__ hout,
    const int* __restrict__ csrF, const int* __restrict__ offF,
    const int* __restrict__ csrR, const int* __restrict__ offR,
    const float* __restrict__ wlF, const float* __restrict__ blF, const float* __restrict__ wrF,
    const float* __restrict__ wlR, const float* __restrict__ blR, const float* __restrict__ wrR,
    int n) {
    __shared__ float WLF[32][33], WRF[32][33], WLR[32][33], WRR[32][33];
    int tid = threadIdx.x;
    for (int idx = tid; idx < 1024; idx += 256) {
        int j = idx >> 5, k = idx & 31;
        WLF[k][j] = wlF[idx];
        WRF[k][j] = wrF[idx];
        WLR[k][j] = wlR[idx];
        WRR[k][j] = wrR[idx];
    }
    __syncthreads();
    int lane  = tid & 31;
    int node  = blockIdx.x * 8 + (tid >> 5);
    int gstep = gridDim.x * 8;
    for (; node < n; node += gstep) {
        float sf = seg_mean(hin, csrF, offF[node], offF[node + 1], lane);
        float sr = seg_mean(hin, csrR, offR[node], offR[node + 1], lane);

        float hr   = hin[node * 32 + lane];
        float accF = blF[lane];
        float accR = blR[lane];
        #pragma unroll
        for (int k = 0; k < 32; ++k) {
            float sfk = __shfl(sf, k, 32);
            float srk = __shfl(sr, k, 32);
            float hk  = __shfl(hr, k, 32);
            accF = fmaf(sfk, WLF[k][lane], accF);
            accF = fmaf(hk,  WRF[k][lane], accF);
            accR = fmaf(srk, WLR[k][lane], accR);
            accR = fmaf(hk,  WRR[k][lane], accR);
        }
        hout[node * 32 + lane] = fmaxf(accF, 0.f) + fmaxf(accR, 0.f);
    }
}

__global__ void k_pair(const float* __restrict__ h, const int* __restrict__ pos1,
                       float* __restrict__ hp, int total) {
    int idx = blockIdx.x * blockDim.x + threadIdx.x;
    int stride = gridDim.x * blockDim.x;
    for (; idx < total; idx += stride) {
        int r = idx >> 5, k = idx & 31;
        int a = pos1[2 * r], b = pos1[2 * r + 1];
        hp[idx] = h[a * 32 + k] * h[b * 32 + k];
    }
}

__global__ void k_final(const float* __restrict__ h, const int* __restrict__ pos2,
                        const float* __restrict__ pw, const float* __restrict__ pb,
                        float* __restrict__ out, int m2) {
    int tid  = threadIdx.x;
    int lane = tid & 31;
    int i    = blockIdx.x * 8 + (tid >> 5);
    if (i >= m2) return;
    int p0 = pos2[2 * i], p1 = pos2[2 * i + 1];
    float v = h[p0 * 32 + lane] * h[p1 * 32 + lane] * pw[lane];
    #pragma unroll
    for (int o = 16; o > 0; o >>= 1) v += __shfl_xor(v, o, 32);
    if (lane == 0) out[i] = v + pb[0];
}

// ---------------- launch ----------------

extern "C" void kernel_launch(void* const* d_in, const int* in_sizes, int n_in,
                              void* d_out, int out_size, void* d_ws, size_t ws_size,
                              hipStream_t stream) {
    const int*   x      = (const int*)d_in[0];
    const int*   edge1  = (const int*)d_in[2];
    const int*   edge2  = (const int*)d_in[3];
    const int*   edge2r = (const int*)d_in[4];
    const int*   pos1   = (const int*)d_in[5];
    const int*   pos2   = (const int*)d_in[6];
    const float* emb    = (const float*)d_in[7];
    const float* gw     = (const float*)d_in[8];
    const float* gb     = (const float*)d_in[9];
    const float* gms    = (const float*)d_in[10];
    const float* c1wl   = (const float*)d_in[11];
    const float* c1bl   = (const float*)d_in[12];
    const float* c1wr   = (const float*)d_in[13];
    const float* c2wl   = (const float*)d_in[14];
    const float* c2bl   = (const float*)d_in[15];
    const float* c2wr   = (const float*)d_in[16];
    const float* c2rwl  = (const float*)d_in[17];
    const float* c2rbl  = (const float*)d_in[18];
    const float* c2rwr  = (const float*)d_in[19];
    const float* pw     = (const float*)d_in[20];
    const float* pb     = (const float*)d_in[21];
    float* out = (float*)d_out;

    char* ws = (char*)d_ws;
    float* hA    = (float*)(ws + OFF_HA);
    float* hB    = (float*)(ws + OFF_HB);
    int*   csrA  = (int*)(ws + OFF_CSRA);
    int*   csrB  = (int*)(ws + OFF_CSRB);
    int*   off1  = (int*)(ws + OFF_OFF1);
    int*   off2  = (int*)(ws + OFF_OFF2);
    int*   off2r = (int*)(ws + OFF_OFF2R);
    int*   cur   = (int*)(ws + OFF_CUR);
    int*   bsum  = (int*)(ws + OFF_BSUM);
    float* stats = (float*)(ws + OFF_STATS);
    float* aff   = (float*)(ws + OFF_AFF);

    hipMemsetAsync(stats, 0, 256, stream);
    hipMemsetAsync(off1, 0, (NN + 1) * sizeof(int), stream);
    hipMemsetAsync(off2, 0, (N2N + 1) * sizeof(int), stream);
    hipMemsetAsync(off2r, 0, (N2N + 1) * sizeof(int), stream);

    // embedding + GraphNorm
    k_embed_stats<<<1024, 256, 0, stream>>>(x, emb, hA, stats, NN);
    k_affine<<<1, 64, 0, stream>>>(stats, gw, gb, gms, aff, NN);
    k_apply_affine<<<2048, 256, 0, stream>>>(hA, aff, NN * 32);

    // CSR for edge1 (into csrA)
    int nb1 = (NN + SCAN_CHUNK - 1) / SCAN_CHUNK;
    k_count<<<2048, 256, 0, stream>>>(edge1 + E1N, off1, E1N);
    k_scan_partial<<<nb1, 256, 0, stream>>>(off1, bsum, NN);
    k_scan_bsum<<<1, 1, 0, stream>>>(bsum, nb1);
    k_scan_final<<<nb1, 256, 0, stream>>>(off1, cur, bsum, NN);
    k_fill<<<2048, 256, 0, stream>>>(edge1, edge1 + E1N, cur, csrA, E1N);

    // conv1: hA -> hB -> hA
    k_sage<<<(NN + 7) / 8, 256, 0, stream>>>(hA, hB, csrA, off1, c1wl, c1bl, c1wr, NN);
    k_sage<<<(NN + 7) / 8, 256, 0, stream>>>(hB, hA, csrA, off1,
                                             c1wl + 1024, c1bl + 32, c1wr + 1024, NN);

    // pair features: hA (N rows) -> hB (N2 rows)
    k_pair<<<2048, 256, 0, stream>>>(hA, pos1, hB, N2N * 32);

    // CSR for edge2 (into csrA, overwriting csr1) and edge2_r (into csrB)
    int nb2 = (N2N + SCAN_CHUNK - 1) / SCAN_CHUNK;
    k_count<<<2048, 256, 0, stream>>>(edge2 + E2N, off2, E2N);
    k_scan_partial<<<nb2, 256, 0, stream>>>(off2, bsum, N2N);
    k_scan_bsum<<<1, 1, 0, stream>>>(bsum, nb2);
    k_scan_final<<<nb2, 256, 0, stream>>>(off2, cur, bsum, N2N);
    k_fill<<<2048, 256, 0, stream>>>(edge2, edge2 + E2N, cur, csrA, E2N);

    k_count<<<2048, 256, 0, stream>>>(edge2r + E2N, off2r, E2N);
    k_scan_partial<<<nb2, 256, 0, stream>>>(off2r, bsum, N2N);
    k_scan_bsum<<<1, 1, 0, stream>>>(bsum, nb2);
    k_scan_final<<<nb2, 256, 0, stream>>>(off2r, cur, bsum, N2N);
    k_fill<<<2048, 256, 0, stream>>>(edge2r, edge2r + E2N, cur, csrB, E2N);

    // conv2: hB -> hA -> hB  (fused forward+reverse each layer)
    k_sage2<<<(N2N + 7) / 8, 256, 0, stream>>>(hB, hA, csrA, off2, csrB, off2r,
        c2wl, c2bl, c2wr, c2rwl, c2rbl, c2rwr, N2N);
    k_sage2<<<(N2N + 7) / 8, 256, 0, stream>>>(hA, hB, csrA, off2, csrB, off2r,
        c2wl + 1024, c2bl + 32, c2wr + 1024, c2rwl + 1024, c2rbl + 32, c2rwr + 1024, N2N);

    // head: gather pos2, even*odd, dot with pred_w
    k_final<<<(MN / 2) / 8, 256, 0, stream>>>(hB, pos2, pw, pb, out, MN / 2);
}

// Round 3
// 2314.051 us; speedup vs baseline: 1.8395x; 1.1453x over previous
//
#include <hip/hip_runtime.h>

#define LATENT 32
#define NN     100000
#define E1N    3200000
#define N2N    200000
#define E2N    3200000
#define MN     131072
#define EPSV   1e-5f

#define SCAN_CHUNK 2048

// ---------------- workspace layout (bytes) ----------------
constexpr size_t OFF_HA    = 0;
constexpr size_t OFF_HB    = OFF_HA    + (size_t)N2N * 32 * 4;   // 25.6 MB each
constexpr size_t OFF_CSRA  = OFF_HB    + (size_t)N2N * 32 * 4;   // 12.8 MB (csr1 then csr2)
constexpr size_t OFF_CSRB  = OFF_CSRA  + (size_t)E2N * 4;        // 12.8 MB (csr2r)
constexpr size_t OFF_OFF1  = OFF_CSRB  + (size_t)E2N * 4;        // (NN+1) ints
constexpr size_t OFF_OFF2  = OFF_OFF1  + 401408;                 // (N2N+1) ints
constexpr size_t OFF_OFF2R = OFF_OFF2  + 801280;
constexpr size_t OFF_CUR   = OFF_OFF2R + 801280;                 // N2N ints
constexpr size_t OFF_BSUM  = OFF_CUR   + 800000;
constexpr size_t OFF_STATS = OFF_BSUM  + 1024;
constexpr size_t OFF_AFF   = OFF_STATS + 256;

// ---------------- kernels ----------------

__global__ void k_embed_stats(const int* __restrict__ x, const float* __restrict__ emb,
                              float* __restrict__ h, float* __restrict__ stats, int n) {
    __shared__ float lsum[256], lsq[256];
    int tid = threadIdx.x;
    float s = 0.f, q = 0.f;
    int stride = gridDim.x * blockDim.x;
    for (int idx = blockIdx.x * blockDim.x + tid; idx < n * 32; idx += stride) {
        int i = idx >> 5, k = idx & 31;
        float v = emb[x[i] * 32 + k];
        h[idx] = v;
        s += v; q += v * v;
    }
    lsum[tid] = s; lsq[tid] = q;
    __syncthreads();
    if (tid < 32) {
        float ts = 0.f, tq = 0.f;
        #pragma unroll
        for (int r = 0; r < 8; ++r) { ts += lsum[tid + r * 32]; tq += lsq[tid + r * 32]; }
        atomicAdd(&stats[tid], ts);
        atomicAdd(&stats[32 + tid], tq);
    }
}

__global__ void k_affine(const float* __restrict__ stats, const float* __restrict__ w,
                         const float* __restrict__ b, const float* __restrict__ ms,
                         float* __restrict__ aff, int n) {
    int k = threadIdx.x;
    if (k < 32) {
        float mean = stats[k] / (float)n;
        float m2   = stats[32 + k] / (float)n;
        float m    = ms[k];
        float var  = m2 - 2.f * m * mean * mean + m * m * mean * mean;
        float A    = w[k] / sqrtf(var + EPSV);
        aff[k]      = A;
        aff[32 + k] = b[k] - A * m * mean;
    }
}

__global__ void k_apply_affine(float* __restrict__ h, const float* __restrict__ aff, int total) {
    int idx = blockIdx.x * blockDim.x + threadIdx.x;
    int stride = gridDim.x * blockDim.x;
    for (; idx < total; idx += stride) {
        int k = idx & 31;
        h[idx] = h[idx] * aff[k] + aff[32 + k];
    }
}

__global__ void k_count(const int* __restrict__ dst, int* __restrict__ off, int ne) {
    int idx = blockIdx.x * blockDim.x + threadIdx.x;
    int stride = gridDim.x * blockDim.x;
    for (; idx < ne; idx += stride) atomicAdd(&off[dst[idx] + 1], 1);
}

__global__ void k_scan_partial(const int* __restrict__ off, int* __restrict__ bsum, int n) {
    __shared__ int lds[256];
    int t = threadIdx.x;
    int base = blockIdx.x * SCAN_CHUNK + t * 8;
    int s = 0;
    #pragma unroll
    for (int j = 0; j < 8; ++j) { int e = base + j; if (e < n) s += off[e + 1]; }
    lds[t] = s; __syncthreads();
    for (int o = 128; o > 0; o >>= 1) { if (t < o) lds[t] += lds[t + o]; __syncthreads(); }
    if (t == 0) bsum[blockIdx.x] = lds[0];
}

__global__ void k_scan_bsum(int* __restrict__ bsum, int nb) {
    if (threadIdx.x == 0 && blockIdx.x == 0) {
        int run = 0;
        for (int j = 0; j < nb; ++j) { int t = bsum[j]; bsum[j] = run; run += t; }
    }
}

__global__ void k_scan_final(int* __restrict__ off, int* __restrict__ cur,
                             const int* __restrict__ bsum, int n) {
    __shared__ int lds[256];
    int t = threadIdx.x;
    int base = blockIdx.x * SCAN_CHUNK + t * 8;
    int v[8]; int run = 0;
    #pragma unroll
    for (int j = 0; j < 8; ++j) {
        int e = base + j;
        v[j] = (e < n) ? off[e + 1] : 0;
        run += v[j];
    }
    int tot = run;
    lds[t] = tot; __syncthreads();
    for (int o = 1; o < 256; o <<= 1) {
        int add = (t >= o) ? lds[t - o] : 0;
        __syncthreads();
        lds[t] += add;
        __syncthreads();
    }
    int excl = lds[t] - tot + bsum[blockIdx.x];
    int run2 = excl;
    #pragma unroll
    for (int j = 0; j < 8; ++j) {
        int e = base + j;
        if (e < n) {
            run2 += v[j];
            off[e + 1] = run2;      // inclusive scan -> off[v] = start of v
            cur[e]     = run2 - v[j];
        }
    }
}

__global__ void k_fill(const int* __restrict__ src, const int* __restrict__ dst,
                       int* __restrict__ cur, int* __restrict__ csr, int ne) {
    int idx = blockIdx.x * blockDim.x + threadIdx.x;
    int stride = gridDim.x * blockDim.x;
    for (; idx < ne; idx += stride) {
        int p = atomicAdd(&cur[dst[idx]], 1);
        csr[p] = src[idx];
    }
}

// segment-mean with coalesced index load (32 idx / 128B transaction) and
// 8 independent gathers in flight; OOB slots branch-free via 0-weight FMA.
__device__ __forceinline__ float seg_mean(const float* __restrict__ hin,
                                          const int* __restrict__ csr,
                                          int s0, int s1, int lane) {
    float a0 = 0.f, a1 = 0.f, a2 = 0.f, a3 = 0.f;
    float a4 = 0.f, a5 = 0.f, a6 = 0.f, a7 = 0.f;
    for (int base = s0; base < s1; base += 32) {
        int e   = base + lane;
        int idx = csr[e < s1 ? e : s1 - 1];     // coalesced; clamp keeps addr valid
        int m   = s1 - base; if (m > 32) m = 32;
        for (int j = 0; j < m; j += 8) {
            #pragma unroll
            for (int k = 0; k < 8; ++k) {
                int   jj  = j + k;
                int   src = __shfl(idx, jj & 31, 32);
                float w   = (jj < m) ? 1.f : 0.f;
                float v   = hin[src * 32 + lane];
                switch (k) {
                    case 0: a0 = fmaf(v, w, a0); break;
                    case 1: a1 = fmaf(v, w, a1); break;
                    case 2: a2 = fmaf(v, w, a2); break;
                    case 3: a3 = fmaf(v, w, a3); break;
                    case 4: a4 = fmaf(v, w, a4); break;
                    case 5: a5 = fmaf(v, w, a5); break;
                    case 6: a6 = fmaf(v, w, a6); break;
                    case 7: a7 = fmaf(v, w, a7); break;
                }
            }
        }
    }
    float s = ((a0 + a1) + (a2 + a3)) + ((a4 + a5) + (a6 + a7));
    int c = s1 - s0;
    return s * (1.0f / (float)(c > 0 ? c : 1));
}

// one 32-lane group per node; lane = feature
__global__ void __launch_bounds__(256) k_sage(
    const float* __restrict__ hin, float* __restrict__ hout,
    const int* __restrict__ csr, const int* __restrict__ off,
    const float* __restrict__ wl, const float* __restrict__ bl, const float* __restrict__ wr,
    int n) {
    __shared__ float wlT[32][33];
    __shared__ float wrT[32][33];
    int tid = threadIdx.x;
    for (int idx = tid; idx < 1024; idx += 256) {
        int j = idx >> 5, k = idx & 31;
        wlT[k][j] = wl[idx];
        wrT[k][j] = wr[idx];
    }
    __syncthreads();
    int lane  = tid & 31;
    int node  = blockIdx.x * 8 + (tid >> 5);
    int gstep = gridDim.x * 8;
    for (; node < n; node += gstep) {
        float s  = seg_mean(hin, csr, off[node], off[node + 1], lane);
        float hr = hin[node * 32 + lane];
        float acc = bl[lane];
        #pragma unroll
        for (int k = 0; k < 32; ++k) {
            float sk = __shfl(s, k, 32);
            float hk = __shfl(hr, k, 32);
            acc = fmaf(sk, wlT[k][lane], acc);
            acc = fmaf(hk, wrT[k][lane], acc);
        }
        hout[node * 32 + lane] = fmaxf(acc, 0.f);
    }
}

// fused dual-direction sage: relu(sageF) + relu(sageR)
__global__ void __launch_bounds__(256) k_sage2(
    const float* __restrict__ hin, float* __restrict__ hout,
    const int* __restrict__ csrF, const int* __restrict__ offF,
    const int* __restrict__ csrR, const int* __restrict__ offR,
    const float* __restrict__ wlF, const float* __restrict__ blF, const float* __restrict__ wrF,
    const float* __restrict__ wlR, const float* __restrict__ blR, const float* __restrict__ wrR,
    int n) {
    __shared__ float WLF[32][33], WRF[32][33], WLR[32][33], WRR[32][33];
    int tid = threadIdx.x;
    for (int idx = tid; idx < 1024; idx += 256) {
        int j = idx >> 5, k = idx & 31;
        WLF[k][j] = wlF[idx];
        WRF[k][j] = wrF[idx];
        WLR[k][j] = wlR[idx];
        WRR[k][j] = wrR[idx];
    }
    __syncthreads();
    int lane  = tid & 31;
    int node  = blockIdx.x * 8 + (tid >> 5);
    int gstep = gridDim.x * 8;
    for (; node < n; node += gstep) {
        float sf = seg_mean(hin, csrF, offF[node], offF[node + 1], lane);
        float sr = seg_mean(hin, csrR, offR[node], offR[node + 1], lane);

        float hr   = hin[node * 32 + lane];
        float accF = blF[lane];
        float accR = blR[lane];
        #pragma unroll
        for (int k = 0; k < 32; ++k) {
            float sfk = __shfl(sf, k, 32);
            float srk = __shfl(sr, k, 32);
            float hk  = __shfl(hr, k, 32);
            accF = fmaf(sfk, WLF[k][lane], accF);
            accF = fmaf(hk,  WRF[k][lane], accF);
            accR = fmaf(srk, WLR[k][lane], accR);
            accR = fmaf(hk,  WRR[k][lane], accR);
        }
        hout[node * 32 + lane] = fmaxf(accF, 0.f) + fmaxf(accR, 0.f);
    }
}

__global__ void k_pair(const float* __restrict__ h, const int* __restrict__ pos1,
                       float* __restrict__ hp, int total) {
    int idx = blockIdx.x * blockDim.x + threadIdx.x;
    int stride = gridDim.x * blockDim.x;
    for (; idx < total; idx += stride) {
        int r = idx >> 5, k = idx & 31;
        int a = pos1[2 * r], b = pos1[2 * r + 1];
        hp[idx] = h[a * 32 + k] * h[b * 32 + k];
    }
}

__global__ void k_final(const float* __restrict__ h, const int* __restrict__ pos2,
                        const float* __restrict__ pw, const float* __restrict__ pb,
                        float* __restrict__ out, int m2) {
    int tid  = threadIdx.x;
    int lane = tid & 31;
    int i    = blockIdx.x * 8 + (tid >> 5);
    if (i >= m2) return;
    int p0 = pos2[2 * i], p1 = pos2[2 * i + 1];
    float v = h[p0 * 32 + lane] * h[p1 * 32 + lane] * pw[lane];
    #pragma unroll
    for (int o = 16; o > 0; o >>= 1) v += __shfl_xor(v, o, 32);
    if (lane == 0) out[i] = v + pb[0];
}

// ---------------- launch ----------------

extern "C" void kernel_launch(void* const* d_in, const int* in_sizes, int n_in,
                              void* d_out, int out_size, void* d_ws, size_t ws_size,
                              hipStream_t stream) {
    const int*   x      = (const int*)d_in[0];
    const int*   edge1  = (const int*)d_in[2];
    const int*   edge2  = (const int*)d_in[3];
    const int*   edge2r = (const int*)d_in[4];
    const int*   pos1   = (const int*)d_in[5];
    const int*   pos2   = (const int*)d_in[6];
    const float* emb    = (const float*)d_in[7];
    const float* gw     = (const float*)d_in[8];
    const float* gb     = (const float*)d_in[9];
    const float* gms    = (const float*)d_in[10];
    const float* c1wl   = (const float*)d_in[11];
    const float* c1bl   = (const float*)d_in[12];
    const float* c1wr   = (const float*)d_in[13];
    const float* c2wl   = (const float*)d_in[14];
    const float* c2bl   = (const float*)d_in[15];
    const float* c2wr   = (const float*)d_in[16];
    const float* c2rwl  = (const float*)d_in[17];
    const float* c2rbl  = (const float*)d_in[18];
    const float* c2rwr  = (const float*)d_in[19];
    const float* pw     = (const float*)d_in[20];
    const float* pb     = (const float*)d_in[21];
    float* out = (float*)d_out;

    char* ws = (char*)d_ws;
    float* hA    = (float*)(ws + OFF_HA);
    float* hB    = (float*)(ws + OFF_HB);
    int*   csrA  = (int*)(ws + OFF_CSRA);
    int*   csrB  = (int*)(ws + OFF_CSRB);
    int*   off1  = (int*)(ws + OFF_OFF1);
    int*   off2  = (int*)(ws + OFF_OFF2);
    int*   off2r = (int*)(ws + OFF_OFF2R);
    int*   cur   = (int*)(ws + OFF_CUR);
    int*   bsum  = (int*)(ws + OFF_BSUM);
    float* stats = (float*)(ws + OFF_STATS);
    float* aff   = (float*)(ws + OFF_AFF);

    hipMemsetAsync(stats, 0, 256, stream);
    hipMemsetAsync(off1, 0, (NN + 1) * sizeof(int), stream);
    hipMemsetAsync(off2, 0, (N2N + 1) * sizeof(int), stream);
    hipMemsetAsync(off2r, 0, (N2N + 1) * sizeof(int), stream);

    // embedding + GraphNorm
    k_embed_stats<<<1024, 256, 0, stream>>>(x, emb, hA, stats, NN);
    k_affine<<<1, 64, 0, stream>>>(stats, gw, gb, gms, aff, NN);
    k_apply_affine<<<2048, 256, 0, stream>>>(hA, aff, NN * 32);

    // CSR for edge1 (into csrA)
    int nb1 = (NN + SCAN_CHUNK - 1) / SCAN_CHUNK;
    k_count<<<2048, 256, 0, stream>>>(edge1 + E1N, off1, E1N);
    k_scan_partial<<<nb1, 256, 0, stream>>>(off1, bsum, NN);
    k_scan_bsum<<<1, 1, 0, stream>>>(bsum, nb1);
    k_scan_final<<<nb1, 256, 0, stream>>>(off1, cur, bsum, NN);
    k_fill<<<2048, 256, 0, stream>>>(edge1, edge1 + E1N, cur, csrA, E1N);

    // conv1: hA -> hB -> hA
    k_sage<<<(NN + 7) / 8, 256, 0, stream>>>(hA, hB, csrA, off1, c1wl, c1bl, c1wr, NN);
    k_sage<<<(NN + 7) / 8, 256, 0, stream>>>(hB, hA, csrA, off1,
                                             c1wl + 1024, c1bl + 32, c1wr + 1024, NN);

    // pair features: hA (N rows) -> hB (N2 rows)
    k_pair<<<2048, 256, 0, stream>>>(hA, pos1, hB, N2N * 32);

    // CSR for edge2 (into csrA, overwriting csr1) and edge2_r (into csrB)
    int nb2 = (N2N + SCAN_CHUNK - 1) / SCAN_CHUNK;
    k_count<<<2048, 256, 0, stream>>>(edge2 + E2N, off2, E2N);
    k_scan_partial<<<nb2, 256, 0, stream>>>(off2, bsum, N2N);
    k_scan_bsum<<<1, 1, 0, stream>>>(bsum, nb2);
    k_scan_final<<<nb2, 256, 0, stream>>>(off2, cur, bsum, N2N);
    k_fill<<<2048, 256, 0, stream>>>(edge2, edge2 + E2N, cur, csrA, E2N);

    k_count<<<2048, 256, 0, stream>>>(edge2r + E2N, off2r, E2N);
    k_scan_partial<<<nb2, 256, 0, stream>>>(off2r, bsum, N2N);
    k_scan_bsum<<<1, 1, 0, stream>>>(bsum, nb2);
    k_scan_final<<<nb2, 256, 0, stream>>>(off2r, cur, bsum, N2N);
    k_fill<<<2048, 256, 0, stream>>>(edge2r, edge2r + E2N, cur, csrB, E2N);

    // conv2: hB -> hA -> hB  (fused forward+reverse each layer)
    k_sage2<<<(N2N + 7) / 8, 256, 0, stream>>>(hB, hA, csrA, off2, csrB, off2r,
        c2wl, c2bl, c2wr, c2rwl, c2rbl, c2rwr, N2N);
    k_sage2<<<(N2N + 7) / 8, 256, 0, stream>>>(hA, hB, csrA, off2, csrB, off2r,
        c2wl + 1024, c2bl + 32, c2wr + 1024, c2rwl + 1024, c2rbl + 32, c2rwr + 1024, N2N);

    // head: gather pos2, even*odd, dot with pred_w
    k_final<<<(MN / 2) / 8, 256, 0, stream>>>(hB, pos2, pw, pb, out, MN / 2);
}

// Round 4
// 2057.373 us; speedup vs baseline: 2.0690x; 1.1248x over previous
//
#include <hip/hip_runtime.h>

#define LATENT 32
#define NN     100000
#define E1N    3200000
#define N2N    200000
#define E2N    3200000
#define MN     131072
#define EPSV   1e-5f

#define SCAN_CHUNK 2048

// ---------------- workspace layout (bytes) ----------------
constexpr size_t OFF_HA    = 0;
constexpr size_t OFF_HB    = OFF_HA    + (size_t)N2N * 32 * 4;   // 25.6 MB each
constexpr size_t OFF_CSRA  = OFF_HB    + (size_t)N2N * 32 * 4;   // 12.8 MB (csr1 then csr2)
constexpr size_t OFF_CSRB  = OFF_CSRA  + (size_t)E2N * 4;        // 12.8 MB (csr2r)
constexpr size_t OFF_OFF1  = OFF_CSRB  + (size_t)E2N * 4;        // (NN+1) ints
constexpr size_t OFF_OFF2  = OFF_OFF1  + 401408;                 // (N2N+1) ints
constexpr size_t OFF_OFF2R = OFF_OFF2  + 801280;
constexpr size_t OFF_CUR   = OFF_OFF2R + 801280;                 // N2N ints
constexpr size_t OFF_BSUM  = OFF_CUR   + 800000;
constexpr size_t OFF_STATS = OFF_BSUM  + 1024;
constexpr size_t OFF_AFF   = OFF_STATS + 256;

// ---------------- kernels ----------------

__global__ void k_embed_stats(const int* __restrict__ x, const float* __restrict__ emb,
                              float* __restrict__ h, float* __restrict__ stats, int n) {
    __shared__ float lsum[256], lsq[256];
    int tid = threadIdx.x;
    float s = 0.f, q = 0.f;
    int stride = gridDim.x * blockDim.x;
    for (int idx = blockIdx.x * blockDim.x + tid; idx < n * 32; idx += stride) {
        int i = idx >> 5, k = idx & 31;
        float v = emb[x[i] * 32 + k];
        h[idx] = v;
        s += v; q += v * v;
    }
    lsum[tid] = s; lsq[tid] = q;
    __syncthreads();
    if (tid < 32) {
        float ts = 0.f, tq = 0.f;
        #pragma unroll
        for (int r = 0; r < 8; ++r) { ts += lsum[tid + r * 32]; tq += lsq[tid + r * 32]; }
        atomicAdd(&stats[tid], ts);
        atomicAdd(&stats[32 + tid], tq);
    }
}

__global__ void k_affine(const float* __restrict__ stats, const float* __restrict__ w,
                         const float* __restrict__ b, const float* __restrict__ ms,
                         float* __restrict__ aff, int n) {
    int k = threadIdx.x;
    if (k < 32) {
        float mean = stats[k] / (float)n;
        float m2   = stats[32 + k] / (float)n;
        float m    = ms[k];
        float var  = m2 - 2.f * m * mean * mean + m * m * mean * mean;
        float A    = w[k] / sqrtf(var + EPSV);
        aff[k]      = A;
        aff[32 + k] = b[k] - A * m * mean;
    }
}

__global__ void k_apply_affine(float* __restrict__ h, const float* __restrict__ aff, int total) {
    int idx = blockIdx.x * blockDim.x + threadIdx.x;
    int stride = gridDim.x * blockDim.x;
    for (; idx < total; idx += stride) {
        int k = idx & 31;
        h[idx] = h[idx] * aff[k] + aff[32 + k];
    }
}

__global__ void k_count(const int* __restrict__ dst, int* __restrict__ off, int ne) {
    int idx = blockIdx.x * blockDim.x + threadIdx.x;
    int stride = gridDim.x * blockDim.x;
    for (; idx < ne; idx += stride) atomicAdd(&off[dst[idx] + 1], 1);
}

__global__ void k_scan_partial(const int* __restrict__ off, int* __restrict__ bsum, int n) {
    __shared__ int lds[256];
    int t = threadIdx.x;
    int base = blockIdx.x * SCAN_CHUNK + t * 8;
    int s = 0;
    #pragma unroll
    for (int j = 0; j < 8; ++j) { int e = base + j; if (e < n) s += off[e + 1]; }
    lds[t] = s; __syncthreads();
    for (int o = 128; o > 0; o >>= 1) { if (t < o) lds[t] += lds[t + o]; __syncthreads(); }
    if (t == 0) bsum[blockIdx.x] = lds[0];
}

__global__ void k_scan_bsum(int* __restrict__ bsum, int nb) {
    if (threadIdx.x == 0 && blockIdx.x == 0) {
        int run = 0;
        for (int j = 0; j < nb; ++j) { int t = bsum[j]; bsum[j] = run; run += t; }
    }
}

__global__ void k_scan_final(int* __restrict__ off, int* __restrict__ cur,
                             const int* __restrict__ bsum, int n) {
    __shared__ int lds[256];
    int t = threadIdx.x;
    int base = blockIdx.x * SCAN_CHUNK + t * 8;
    int v[8]; int run = 0;
    #pragma unroll
    for (int j = 0; j < 8; ++j) {
        int e = base + j;
        v[j] = (e < n) ? off[e + 1] : 0;
        run += v[j];
    }
    int tot = run;
    lds[t] = tot; __syncthreads();
    for (int o = 1; o < 256; o <<= 1) {
        int add = (t >= o) ? lds[t - o] : 0;
        __syncthreads();
        lds[t] += add;
        __syncthreads();
    }
    int excl = lds[t] - tot + bsum[blockIdx.x];
    int run2 = excl;
    #pragma unroll
    for (int j = 0; j < 8; ++j) {
        int e = base + j;
        if (e < n) {
            run2 += v[j];
            off[e + 1] = run2;      // inclusive scan -> off[v] = start of v
            cur[e]     = run2 - v[j];
        }
    }
}

__global__ void k_fill(const int* __restrict__ src, const int* __restrict__ dst,
                       int* __restrict__ cur, int* __restrict__ csr, int ne) {
    int idx = blockIdx.x * blockDim.x + threadIdx.x;
    int stride = gridDim.x * blockDim.x;
    for (; idx < ne; idx += stride) {
        int p = atomicAdd(&cur[dst[idx]], 1);
        csr[p] = src[idx];
    }
}

// single-stream segment mean (tail path): 8 gathers in flight
__device__ __forceinline__ float seg_mean(const float* __restrict__ hin,
                                          const int* __restrict__ csr,
                                          int s0, int s1, int lane) {
    float a[8];
    #pragma unroll
    for (int k = 0; k < 8; ++k) a[k] = 0.f;
    for (int base = s0; base < s1; base += 32) {
        int e   = base + lane;
        int idx = csr[e < s1 ? e : s1 - 1];
        int m   = s1 - base; if (m > 32) m = 32;
        for (int j = 0; j < m; j += 8) {
            float v[8];
            #pragma unroll
            for (int k = 0; k < 8; ++k)
                v[k] = hin[__shfl(idx, (j + k) & 31, 32) * 32 + lane];
            #pragma unroll
            for (int k = 0; k < 8; ++k) {
                float w = (j + k < m) ? 1.f : 0.f;
                a[k] = fmaf(v[k], w, a[k]);
            }
        }
    }
    float s = ((a[0] + a[1]) + (a[2] + a[3])) + ((a[4] + a[5]) + (a[6] + a[7]));
    int c = s1 - s0;
    return s * (1.0f / (float)(c > 0 ? c : 1));
}

// dual-stream segment mean: 16 independent gathers in flight.
// Streams may be different CSR ranges (F/R of one node, or two nodes).
__device__ __forceinline__ void seg_mean_dual(const float* __restrict__ hin,
                                              const int* __restrict__ csr0, int s00, int s01,
                                              const int* __restrict__ csr1, int s10, int s11,
                                              int lane, float& out0, float& out1) {
    float a[8], b[8];
    #pragma unroll
    for (int k = 0; k < 8; ++k) { a[k] = 0.f; b[k] = 0.f; }
    int base0 = s00, base1 = s10;
    while (base0 < s01 || base1 < s11) {
        int idx0 = 0, idx1 = 0, m0 = 0, m1 = 0;
        if (base0 < s01) {
            int e = base0 + lane;
            idx0 = csr0[e < s01 ? e : s01 - 1];
            m0 = s01 - base0; if (m0 > 32) m0 = 32;
        }
        if (base1 < s11) {
            int e = base1 + lane;
            idx1 = csr1[e < s11 ? e : s11 - 1];
            m1 = s11 - base1; if (m1 > 32) m1 = 32;
        }
        int mm = m0 > m1 ? m0 : m1;
        for (int j = 0; j < mm; j += 8) {
            float v0[8], v1[8];
            bool d0 = j < m0, d1 = j < m1;
            if (d0) {
                #pragma unroll
                for (int k = 0; k < 8; ++k)
                    v0[k] = hin[__shfl(idx0, (j + k) & 31, 32) * 32 + lane];
            }
            if (d1) {
                #pragma unroll
                for (int k = 0; k < 8; ++k)
                    v1[k] = hin[__shfl(idx1, (j + k) & 31, 32) * 32 + lane];
            }
            if (d0) {
                #pragma unroll
                for (int k = 0; k < 8; ++k) {
                    float w = (j + k < m0) ? 1.f : 0.f;
                    a[k] = fmaf(v0[k], w, a[k]);
                }
            }
            if (d1) {
                #pragma unroll
                for (int k = 0; k < 8; ++k) {
                    float w = (j + k < m1) ? 1.f : 0.f;
                    b[k] = fmaf(v1[k], w, b[k]);
                }
            }
        }
        base0 += 32; base1 += 32;
    }
    float sa = ((a[0] + a[1]) + (a[2] + a[3])) + ((a[4] + a[5]) + (a[6] + a[7]));
    float sb = ((b[0] + b[1]) + (b[2] + b[3])) + ((b[4] + b[5]) + (b[6] + b[7]));
    int c0 = s01 - s00, c1 = s11 - s10;
    out0 = sa * (1.0f / (float)(c0 > 0 ? c0 : 1));
    out1 = sb * (1.0f / (float)(c1 > 0 ? c1 : 1));
}

// one 32-lane group per TWO nodes (node i and i+G), 16 gathers in flight
__global__ void __launch_bounds__(256) k_sage(
    const float* __restrict__ hin, float* __restrict__ hout,
    const int* __restrict__ csr, const int* __restrict__ off,
    const float* __restrict__ wl, const float* __restrict__ bl, const float* __restrict__ wr,
    int n) {
    __shared__ float wlT[32][33];
    __shared__ float wrT[32][33];
    int tid = threadIdx.x;
    for (int idx = tid; idx < 1024; idx += 256) {
        int j = idx >> 5, k = idx & 31;
        wlT[k][j] = wl[idx];
        wrT[k][j] = wr[idx];
    }
    __syncthreads();
    int lane = tid & 31;
    int g    = blockIdx.x * 8 + (tid >> 5);
    int G    = gridDim.x * 8;
    for (int i = g; i < n; i += 2 * G) {
        int n0 = i, n1 = i + G;
        if (n1 < n) {
            float s0, s1;
            seg_mean_dual(hin, csr, off[n0], off[n0 + 1], csr, off[n1], off[n1 + 1],
                          lane, s0, s1);
            float h0 = hin[n0 * 32 + lane];
            float h1 = hin[n1 * 32 + lane];
            float acc0 = bl[lane];
            float acc1 = bl[lane];
            #pragma unroll
            for (int k = 0; k < 32; ++k) {
                float wlk = wlT[k][lane], wrk = wrT[k][lane];
                acc0 = fmaf(__shfl(s0, k, 32), wlk, acc0);
                acc0 = fmaf(__shfl(h0, k, 32), wrk, acc0);
                acc1 = fmaf(__shfl(s1, k, 32), wlk, acc1);
                acc1 = fmaf(__shfl(h1, k, 32), wrk, acc1);
            }
            hout[n0 * 32 + lane] = fmaxf(acc0, 0.f);
            hout[n1 * 32 + lane] = fmaxf(acc1, 0.f);
        } else {
            float s0 = seg_mean(hin, csr, off[n0], off[n0 + 1], lane);
            float h0 = hin[n0 * 32 + lane];
            float acc0 = bl[lane];
            #pragma unroll
            for (int k = 0; k < 32; ++k) {
                acc0 = fmaf(__shfl(s0, k, 32), wlT[k][lane], acc0);
                acc0 = fmaf(__shfl(h0, k, 32), wrT[k][lane], acc0);
            }
            hout[n0 * 32 + lane] = fmaxf(acc0, 0.f);
        }
    }
}

// fused dual-direction sage: relu(sageF) + relu(sageR); F/R gathers interleaved
__global__ void __launch_bounds__(256) k_sage2(
    const float* __restrict__ hin, float* __restrict__ hout,
    const int* __restrict__ csrF, const int* __restrict__ offF,
    const int* __restrict__ csrR, const int* __restrict__ offR,
    const float* __restrict__ wlF, const float* __restrict__ blF, const float* __restrict__ wrF,
    const float* __restrict__ wlR, const float* __restrict__ blR, const float* __restrict__ wrR,
    int n) {
    __shared__ float WLF[32][33], WRF[32][33], WLR[32][33], WRR[32][33];
    int tid = threadIdx.x;
    for (int idx = tid; idx < 1024; idx += 256) {
        int j = idx >> 5, k = idx & 31;
        WLF[k][j] = wlF[idx];
        WRF[k][j] = wrF[idx];
        WLR[k][j] = wlR[idx];
        WRR[k][j] = wrR[idx];
    }
    __syncthreads();
    int lane = tid & 31;
    int g    = blockIdx.x * 8 + (tid >> 5);
    int G    = gridDim.x * 8;
    for (int node = g; node < n; node += G) {
        float sf, sr;
        seg_mean_dual(hin, csrF, offF[node], offF[node + 1],
                      csrR, offR[node], offR[node + 1], lane, sf, sr);
        float hr   = hin[node * 32 + lane];
        float accF = blF[lane];
        float accR = blR[lane];
        #pragma unroll
        for (int k = 0; k < 32; ++k) {
            float sfk = __shfl(sf, k, 32);
            float srk = __shfl(sr, k, 32);
            float hk  = __shfl(hr, k, 32);
            accF = fmaf(sfk, WLF[k][lane], accF);
            accF = fmaf(hk,  WRF[k][lane], accF);
            accR = fmaf(srk, WLR[k][lane], accR);
            accR = fmaf(hk,  WRR[k][lane], accR);
        }
        hout[node * 32 + lane] = fmaxf(accF, 0.f) + fmaxf(accR, 0.f);
    }
}

__global__ void k_pair(const float* __restrict__ h, const int* __restrict__ pos1,
                       float* __restrict__ hp, int total) {
    int idx = blockIdx.x * blockDim.x + threadIdx.x;
    int stride = gridDim.x * blockDim.x;
    for (; idx < total; idx += stride) {
        int r = idx >> 5, k = idx & 31;
        int a = pos1[2 * r], b = pos1[2 * r + 1];
        hp[idx] = h[a * 32 + k] * h[b * 32 + k];
    }
}

__global__ void k_final(const float* __restrict__ h, const int* __restrict__ pos2,
                        const float* __restrict__ pw, const float* __restrict__ pb,
                        float* __restrict__ out, int m2) {
    int tid  = threadIdx.x;
    int lane = tid & 31;
    int i    = blockIdx.x * 8 + (tid >> 5);
    if (i >= m2) return;
    int p0 = pos2[2 * i], p1 = pos2[2 * i + 1];
    float v = h[p0 * 32 + lane] * h[p1 * 32 + lane] * pw[lane];
    #pragma unroll
    for (int o = 16; o > 0; o >>= 1) v += __shfl_xor(v, o, 32);
    if (lane == 0) out[i] = v + pb[0];
}

// ---------------- launch ----------------

extern "C" void kernel_launch(void* const* d_in, const int* in_sizes, int n_in,
                              void* d_out, int out_size, void* d_ws, size_t ws_size,
                              hipStream_t stream) {
    const int*   x      = (const int*)d_in[0];
    const int*   edge1  = (const int*)d_in[2];
    const int*   edge2  = (const int*)d_in[3];
    const int*   edge2r = (const int*)d_in[4];
    const int*   pos1   = (const int*)d_in[5];
    const int*   pos2   = (const int*)d_in[6];
    const float* emb    = (const float*)d_in[7];
    const float* gw     = (const float*)d_in[8];
    const float* gb     = (const float*)d_in[9];
    const float* gms    = (const float*)d_in[10];
    const float* c1wl   = (const float*)d_in[11];
    const float* c1bl   = (const float*)d_in[12];
    const float* c1wr   = (const float*)d_in[13];
    const float* c2wl   = (const float*)d_in[14];
    const float* c2bl   = (const float*)d_in[15];
    const float* c2wr   = (const float*)d_in[16];
    const float* c2rwl  = (const float*)d_in[17];
    const float* c2rbl  = (const float*)d_in[18];
    const float* c2rwr  = (const float*)d_in[19];
    const float* pw     = (const float*)d_in[20];
    const float* pb     = (const float*)d_in[21];
    float* out = (float*)d_out;

    char* ws = (char*)d_ws;
    float* hA    = (float*)(ws + OFF_HA);
    float* hB    = (float*)(ws + OFF_HB);
    int*   csrA  = (int*)(ws + OFF_CSRA);
    int*   csrB  = (int*)(ws + OFF_CSRB);
    int*   off1  = (int*)(ws + OFF_OFF1);
    int*   off2  = (int*)(ws + OFF_OFF2);
    int*   off2r = (int*)(ws + OFF_OFF2R);
    int*   cur   = (int*)(ws + OFF_CUR);
    int*   bsum  = (int*)(ws + OFF_BSUM);
    float* stats = (float*)(ws + OFF_STATS);
    float* aff   = (float*)(ws + OFF_AFF);

    hipMemsetAsync(stats, 0, 256, stream);
    hipMemsetAsync(off1, 0, (NN + 1) * sizeof(int), stream);
    hipMemsetAsync(off2, 0, (N2N + 1) * sizeof(int), stream);
    hipMemsetAsync(off2r, 0, (N2N + 1) * sizeof(int), stream);

    // embedding + GraphNorm
    k_embed_stats<<<1024, 256, 0, stream>>>(x, emb, hA, stats, NN);
    k_affine<<<1, 64, 0, stream>>>(stats, gw, gb, gms, aff, NN);
    k_apply_affine<<<2048, 256, 0, stream>>>(hA, aff, NN * 32);

    // CSR for edge1 (into csrA)
    int nb1 = (NN + SCAN_CHUNK - 1) / SCAN_CHUNK;
    k_count<<<2048, 256, 0, stream>>>(edge1 + E1N, off1, E1N);
    k_scan_partial<<<nb1, 256, 0, stream>>>(off1, bsum, NN);
    k_scan_bsum<<<1, 1, 0, stream>>>(bsum, nb1);
    k_scan_final<<<nb1, 256, 0, stream>>>(off1, cur, bsum, NN);
    k_fill<<<2048, 256, 0, stream>>>(edge1, edge1 + E1N, cur, csrA, E1N);

    // conv1: hA -> hB -> hA
    k_sage<<<4096, 256, 0, stream>>>(hA, hB, csrA, off1, c1wl, c1bl, c1wr, NN);
    k_sage<<<4096, 256, 0, stream>>>(hB, hA, csrA, off1,
                                     c1wl + 1024, c1bl + 32, c1wr + 1024, NN);

    // pair features: hA (N rows) -> hB (N2 rows)
    k_pair<<<2048, 256, 0, stream>>>(hA, pos1, hB, N2N * 32);

    // CSR for edge2 (into csrA, overwriting csr1) and edge2_r (into csrB)
    int nb2 = (N2N + SCAN_CHUNK - 1) / SCAN_CHUNK;
    k_count<<<2048, 256, 0, stream>>>(edge2 + E2N, off2, E2N);
    k_scan_partial<<<nb2, 256, 0, stream>>>(off2, bsum, N2N);
    k_scan_bsum<<<1, 1, 0, stream>>>(bsum, nb2);
    k_scan_final<<<nb2, 256, 0, stream>>>(off2, cur, bsum, N2N);
    k_fill<<<2048, 256, 0, stream>>>(edge2, edge2 + E2N, cur, csrA, E2N);

    k_count<<<2048, 256, 0, stream>>>(edge2r + E2N, off2r, E2N);
    k_scan_partial<<<nb2, 256, 0, stream>>>(off2r, bsum, N2N);
    k_scan_bsum<<<1, 1, 0, stream>>>(bsum, nb2);
    k_scan_final<<<nb2, 256, 0, stream>>>(off2r, cur, bsum, N2N);
    k_fill<<<2048, 256, 0, stream>>>(edge2r, edge2r + E2N, cur, csrB, E2N);

    // conv2: hB -> hA -> hB  (fused forward+reverse each layer)
    k_sage2<<<4096, 256, 0, stream>>>(hB, hA, csrA, off2, csrB, off2r,
        c2wl, c2bl, c2wr, c2rwl, c2rbl, c2rwr, N2N);
    k_sage2<<<4096, 256, 0, stream>>>(hA, hB, csrA, off2, csrB, off2r,
        c2wl + 1024, c2bl + 32, c2wr + 1024, c2rwl + 1024, c2rbl + 32, c2rwr + 1024, N2N);

    // head: gather pos2, even*odd, dot with pred_w
    k_final<<<(MN / 2) / 8, 256, 0, stream>>>(hB, pos2, pw, pb, out, MN / 2);
}

// Round 5
// 2022.983 us; speedup vs baseline: 2.1042x; 1.0170x over previous
//
#include <hip/hip_runtime.h>

#define LATENT 32
#define NN     100000
#define E1N    3200000
#define N2N    200000
#define E2N    3200000
#define MN     131072
#define EPSV   1e-5f

#define SCAN_CHUNK 2048

// ---------------- workspace layout (bytes) ----------------
constexpr size_t OFF_HA    = 0;
constexpr size_t OFF_HB    = OFF_HA    + (size_t)N2N * 32 * 4;   // 25.6 MB each
constexpr size_t OFF_CSRA  = OFF_HB    + (size_t)N2N * 32 * 4;   // 12.8 MB (csr1 then csr2)
constexpr size_t OFF_CSRB  = OFF_CSRA  + (size_t)E2N * 4;        // 12.8 MB (csr2r)
constexpr size_t OFF_OFF1  = OFF_CSRB  + (size_t)E2N * 4;        // (NN+1) ints
constexpr size_t OFF_OFF2  = OFF_OFF1  + 401408;                 // (N2N+1) ints
constexpr size_t OFF_OFF2R = OFF_OFF2  + 801280;
constexpr size_t OFF_CUR   = OFF_OFF2R + 801280;                 // N2N ints
constexpr size_t OFF_CUR2R = OFF_CUR   + 800000;                 // N2N ints
constexpr size_t OFF_BSUMA = OFF_CUR2R + 800000;
constexpr size_t OFF_BSUMB = OFF_BSUMA + 512;
constexpr size_t OFF_BSUMC = OFF_BSUMB + 512;
constexpr size_t OFF_STATS = OFF_BSUMC + 512;
constexpr size_t OFF_AFF   = OFF_STATS + 256;

// ---------------- kernels ----------------

__global__ void k_embed_stats(const int* __restrict__ x, const float* __restrict__ emb,
                              float* __restrict__ h, float* __restrict__ stats, int n) {
    __shared__ float lsum[256], lsq[256];
    int tid = threadIdx.x;
    float s = 0.f, q = 0.f;
    int stride = gridDim.x * blockDim.x;
    for (int idx = blockIdx.x * blockDim.x + tid; idx < n * 32; idx += stride) {
        int i = idx >> 5, k = idx & 31;
        float v = emb[x[i] * 32 + k];
        h[idx] = v;
        s += v; q += v * v;
    }
    lsum[tid] = s; lsq[tid] = q;
    __syncthreads();
    if (tid < 32) {
        float ts = 0.f, tq = 0.f;
        #pragma unroll
        for (int r = 0; r < 8; ++r) { ts += lsum[tid + r * 32]; tq += lsq[tid + r * 32]; }
        atomicAdd(&stats[tid], ts);
        atomicAdd(&stats[32 + tid], tq);
    }
}

__global__ void k_affine(const float* __restrict__ stats, const float* __restrict__ w,
                         const float* __restrict__ b, const float* __restrict__ ms,
                         float* __restrict__ aff, int n) {
    int k = threadIdx.x;
    if (k < 32) {
        float mean = stats[k] / (float)n;
        float m2   = stats[32 + k] / (float)n;
        float m    = ms[k];
        float var  = m2 - 2.f * m * mean * mean + m * m * mean * mean;
        float A    = w[k] / sqrtf(var + EPSV);
        aff[k]      = A;
        aff[32 + k] = b[k] - A * m * mean;
    }
}

__global__ void k_apply_affine(float* __restrict__ h, const float* __restrict__ aff, int total) {
    int idx = blockIdx.x * blockDim.x + threadIdx.x;
    int stride = gridDim.x * blockDim.x;
    for (; idx < total; idx += stride) {
        int k = idx & 31;
        h[idx] = h[idx] * aff[k] + aff[32 + k];
    }
}

__global__ void k_count(const int* __restrict__ dst, int* __restrict__ off, int ne) {
    int idx = blockIdx.x * blockDim.x + threadIdx.x;
    int stride = gridDim.x * blockDim.x;
    for (; idx < ne; idx += stride) atomicAdd(&off[dst[idx] + 1], 1);
}

// fused count for two edge lists (pair graph F and R)
__global__ void k_count2(const int* __restrict__ dstF, int* __restrict__ offF,
                         const int* __restrict__ dstR, int* __restrict__ offR, int ne) {
    int idx = blockIdx.x * blockDim.x + threadIdx.x;
    int stride = gridDim.x * blockDim.x;
    for (; idx < 2 * ne; idx += stride) {
        if (idx < ne) atomicAdd(&offF[dstF[idx] + 1], 1);
        else          atomicAdd(&offR[dstR[idx - ne] + 1], 1);
    }
}

__device__ __forceinline__ void scan_partial_body(const int* __restrict__ off,
                                                  int* __restrict__ bsum, int n, int blk) {
    __shared__ int lds[256];
    int t = threadIdx.x;
    int base = blk * SCAN_CHUNK + t * 8;
    int s = 0;
    #pragma unroll
    for (int j = 0; j < 8; ++j) { int e = base + j; if (e < n) s += off[e + 1]; }
    lds[t] = s; __syncthreads();
    for (int o = 128; o > 0; o >>= 1) { if (t < o) lds[t] += lds[t + o]; __syncthreads(); }
    if (t == 0) bsum[blk] = lds[0];
}

__global__ void k_scan_partial(const int* __restrict__ off, int* __restrict__ bsum, int n) {
    scan_partial_body(off, bsum, n, blockIdx.x);
}

__global__ void k_scan_partial2(const int* __restrict__ o1, int* __restrict__ b1,
                                const int* __restrict__ o2, int* __restrict__ b2,
                                int n, int nb) {
    int blk = blockIdx.x;
    if (blk < nb) scan_partial_body(o1, b1, n, blk);
    else          scan_partial_body(o2, b2, n, blk - nb);
}

// parallel exclusive scan of the per-block sums (<=128 entries per array)
__global__ void k_scan_bsum2(int* __restrict__ bA, int nA, int* __restrict__ bB, int nB) {
    int* b = (blockIdx.x == 0) ? bA : bB;
    int n  = (blockIdx.x == 0) ? nA : nB;
    __shared__ int lds[128];
    int t = threadIdx.x;
    int v = (t < n) ? b[t] : 0;
    lds[t] = v; __syncthreads();
    for (int o = 1; o < 128; o <<= 1) {
        int add = (t >= o) ? lds[t - o] : 0;
        __syncthreads();
        lds[t] += add;
        __syncthreads();
    }
    if (t < n) b[t] = lds[t] - v;   // exclusive
}

__device__ __forceinline__ void scan_final_body(int* __restrict__ off, int* __restrict__ cur,
                                                const int* __restrict__ bsum, int n, int blk) {
    __shared__ int lds[256];
    int t = threadIdx.x;
    int base = blk * SCAN_CHUNK + t * 8;
    int v[8]; int run = 0;
    #pragma unroll
    for (int j = 0; j < 8; ++j) {
        int e = base + j;
        v[j] = (e < n) ? off[e + 1] : 0;
        run += v[j];
    }
    int tot = run;
    lds[t] = tot; __syncthreads();
    for (int o = 1; o < 256; o <<= 1) {
        int add = (t >= o) ? lds[t - o] : 0;
        __syncthreads();
        lds[t] += add;
        __syncthreads();
    }
    int excl = lds[t] - tot + bsum[blk];
    int run2 = excl;
    #pragma unroll
    for (int j = 0; j < 8; ++j) {
        int e = base + j;
        if (e < n) {
            run2 += v[j];
            off[e + 1] = run2;      // inclusive scan -> off[v] = start of v
            cur[e]     = run2 - v[j];
        }
    }
}

__global__ void k_scan_final(int* __restrict__ off, int* __restrict__ cur,
                             const int* __restrict__ bsum, int n) {
    scan_final_body(off, cur, bsum, n, blockIdx.x);
}

__global__ void k_scan_final2(int* __restrict__ o1, int* __restrict__ c1, const int* __restrict__ b1,
                              int* __restrict__ o2, int* __restrict__ c2, const int* __restrict__ b2,
                              int n, int nb) {
    int blk = blockIdx.x;
    if (blk < nb) scan_final_body(o1, c1, b1, n, blk);
    else          scan_final_body(o2, c2, b2, n, blk - nb);
}

__global__ void k_fill(const int* __restrict__ src, const int* __restrict__ dst,
                       int* __restrict__ cur, int* __restrict__ csr, int ne) {
    int idx = blockIdx.x * blockDim.x + threadIdx.x;
    int stride = gridDim.x * blockDim.x;
    for (; idx < ne; idx += stride) {
        int p = atomicAdd(&cur[dst[idx]], 1);
        csr[p] = src[idx];
    }
}

__global__ void k_fill2(const int* __restrict__ srcF, const int* __restrict__ dstF,
                        int* __restrict__ curF, int* __restrict__ csrF,
                        const int* __restrict__ srcR, const int* __restrict__ dstR,
                        int* __restrict__ curR, int* __restrict__ csrR, int ne) {
    int idx = blockIdx.x * blockDim.x + threadIdx.x;
    int stride = gridDim.x * blockDim.x;
    for (; idx < 2 * ne; idx += stride) {
        if (idx < ne) {
            int p = atomicAdd(&curF[dstF[idx]], 1);
            csrF[p] = srcF[idx];
        } else {
            int e = idx - ne;
            int p = atomicAdd(&curR[dstR[e]], 1);
            csrR[p] = srcR[e];
        }
    }
}

// quad-stream segment mean: up to 32 independent gathers in flight.
__device__ __forceinline__ void seg_mean_quad(
    const float* __restrict__ hin,
    const int* __restrict__ cA, int a0, int a1,
    const int* __restrict__ cB, int b0, int b1,
    const int* __restrict__ cC, int c0, int c1,
    const int* __restrict__ cD, int d0, int d1,
    int lane, float& oA, float& oB, float& oC, float& oD)
{
    float aA[4], aB[4], aC[4], aD[4];
    #pragma unroll
    for (int k = 0; k < 4; ++k) { aA[k] = 0.f; aB[k] = 0.f; aC[k] = 0.f; aD[k] = 0.f; }
    int pA = a0, pB = b0, pC = c0, pD = d0;
    while (pA < a1 || pB < b1 || pC < c1 || pD < d1) {
        int iA = 0, iB = 0, iC = 0, iD = 0, mA = 0, mB = 0, mC = 0, mD = 0;
        if (pA < a1) { int e = pA + lane; iA = cA[e < a1 ? e : a1 - 1]; mA = a1 - pA; if (mA > 32) mA = 32; }
        if (pB < b1) { int e = pB + lane; iB = cB[e < b1 ? e : b1 - 1]; mB = b1 - pB; if (mB > 32) mB = 32; }
        if (pC < c1) { int e = pC + lane; iC = cC[e < c1 ? e : c1 - 1]; mC = c1 - pC; if (mC > 32) mC = 32; }
        if (pD < d1) { int e = pD + lane; iD = cD[e < d1 ? e : d1 - 1]; mD = d1 - pD; if (mD > 32) mD = 32; }
        int mm = mA > mB ? mA : mB;
        if (mC > mm) mm = mC;
        if (mD > mm) mm = mD;
        for (int j = 0; j < mm; j += 8) {
            float vA[8], vB[8], vC[8], vD[8];
            bool dA = j < mA, dB = j < mB, dC = j < mC, dD = j < mD;
            if (dA) {
                #pragma unroll
                for (int k = 0; k < 8; ++k)
                    vA[k] = hin[__shfl(iA, (j + k) & 31, 32) * 32 + lane];
            }
            if (dB) {
                #pragma unroll
                for (int k = 0; k < 8; ++k)
                    vB[k] = hin[__shfl(iB, (j + k) & 31, 32) * 32 + lane];
            }
            if (dC) {
                #pragma unroll
                for (int k = 0; k < 8; ++k)
                    vC[k] = hin[__shfl(iC, (j + k) & 31, 32) * 32 + lane];
            }
            if (dD) {
                #pragma unroll
                for (int k = 0; k < 8; ++k)
                    vD[k] = hin[__shfl(iD, (j + k) & 31, 32) * 32 + lane];
            }
            if (dA) {
                #pragma unroll
                for (int k = 0; k < 8; ++k)
                    aA[k & 3] = fmaf(vA[k], (j + k < mA) ? 1.f : 0.f, aA[k & 3]);
            }
            if (dB) {
                #pragma unroll
                for (int k = 0; k < 8; ++k)
                    aB[k & 3] = fmaf(vB[k], (j + k < mB) ? 1.f : 0.f, aB[k & 3]);
            }
            if (dC) {
                #pragma unroll
                for (int k = 0; k < 8; ++k)
                    aC[k & 3] = fmaf(vC[k], (j + k < mC) ? 1.f : 0.f, aC[k & 3]);
            }
            if (dD) {
                #pragma unroll
                for (int k = 0; k < 8; ++k)
                    aD[k & 3] = fmaf(vD[k], (j + k < mD) ? 1.f : 0.f, aD[k & 3]);
            }
        }
        pA += 32; pB += 32; pC += 32; pD += 32;
    }
    int nA = a1 - a0, nB = b1 - b0, nC = c1 - c0, nD = d1 - d0;
    oA = ((aA[0] + aA[1]) + (aA[2] + aA[3])) * (1.0f / (float)(nA > 0 ? nA : 1));
    oB = ((aB[0] + aB[1]) + (aB[2] + aB[3])) * (1.0f / (float)(nB > 0 ? nB : 1));
    oC = ((aC[0] + aC[1]) + (aC[2] + aC[3])) * (1.0f / (float)(nC > 0 ? nC : 1));
    oD = ((aD[0] + aD[1]) + (aD[2] + aD[3])) * (1.0f / (float)(nD > 0 ? nD : 1));
}

// one 32-lane group per FOUR consecutive nodes (n divisible by 4)
__global__ void __launch_bounds__(256) k_sage(
    const float* __restrict__ hin, float* __restrict__ hout,
    const int* __restrict__ csr, const int* __restrict__ off,
    const float* __restrict__ wl, const float* __restrict__ bl, const float* __restrict__ wr,
    int n) {
    __shared__ float wlT[32][33];
    __shared__ float wrT[32][33];
    int tid = threadIdx.x;
    for (int idx = tid; idx < 1024; idx += 256) {
        int j = idx >> 5, k = idx & 31;
        wlT[k][j] = wl[idx];
        wrT[k][j] = wr[idx];
    }
    __syncthreads();
    int lane = tid & 31;
    int g    = blockIdx.x * 8 + (tid >> 5);
    int G    = gridDim.x * 8;
    for (int i = 4 * g; i < n; i += 4 * G) {
        int n0 = i, n1 = i + 1, n2 = i + 2, n3 = i + 3;
        float s0, s1, s2, s3;
        seg_mean_quad(hin, csr, off[n0], off[n0 + 1], csr, off[n1], off[n1 + 1],
                      csr, off[n2], off[n2 + 1], csr, off[n3], off[n3 + 1],
                      lane, s0, s1, s2, s3);
        float h0 = hin[n0 * 32 + lane];
        float h1 = hin[n1 * 32 + lane];
        float h2 = hin[n2 * 32 + lane];
        float h3 = hin[n3 * 32 + lane];
        float bb = bl[lane];
        float A0 = bb, A1 = bb, A2 = bb, A3 = bb;
        #pragma unroll
        for (int k = 0; k < 32; ++k) {
            float wlk = wlT[k][lane], wrk = wrT[k][lane];
            A0 = fmaf(__shfl(s0, k, 32), wlk, A0);
            A0 = fmaf(__shfl(h0, k, 32), wrk, A0);
            A1 = fmaf(__shfl(s1, k, 32), wlk, A1);
            A1 = fmaf(__shfl(h1, k, 32), wrk, A1);
            A2 = fmaf(__shfl(s2, k, 32), wlk, A2);
            A2 = fmaf(__shfl(h2, k, 32), wrk, A2);
            A3 = fmaf(__shfl(s3, k, 32), wlk, A3);
            A3 = fmaf(__shfl(h3, k, 32), wrk, A3);
        }
        hout[n0 * 32 + lane] = fmaxf(A0, 0.f);
        hout[n1 * 32 + lane] = fmaxf(A1, 0.f);
        hout[n2 * 32 + lane] = fmaxf(A2, 0.f);
        hout[n3 * 32 + lane] = fmaxf(A3, 0.f);
    }
}

// fused dual-direction sage over TWO consecutive nodes (n even):
// 4 gather streams (n0F, n0R, n1F, n1R) interleaved
__global__ void __launch_bounds__(256) k_sage2(
    const float* __restrict__ hin, float* __restrict__ hout,
    const int* __restrict__ csrF, const int* __restrict__ offF,
    const int* __restrict__ csrR, const int* __restrict__ offR,
    const float* __restrict__ wlF, const float* __restrict__ blF, const float* __restrict__ wrF,
    const float* __restrict__ wlR, const float* __restrict__ blR, const float* __restrict__ wrR,
    int n) {
    __shared__ float WLF[32][33], WRF[32][33], WLR[32][33], WRR[32][33];
    int tid = threadIdx.x;
    for (int idx = tid; idx < 1024; idx += 256) {
        int j = idx >> 5, k = idx & 31;
        WLF[k][j] = wlF[idx];
        WRF[k][j] = wrF[idx];
        WLR[k][j] = wlR[idx];
        WRR[k][j] = wrR[idx];
    }
    __syncthreads();
    int lane = tid & 31;
    int g    = blockIdx.x * 8 + (tid >> 5);
    int G    = gridDim.x * 8;
    for (int i = 2 * g; i < n; i += 2 * G) {
        int n0 = i, n1 = i + 1;
        float sF0, sR0, sF1, sR1;
        seg_mean_quad(hin, csrF, offF[n0], offF[n0 + 1], csrR, offR[n0], offR[n0 + 1],
                      csrF, offF[n1], offF[n1 + 1], csrR, offR[n1], offR[n1 + 1],
                      lane, sF0, sR0, sF1, sR1);
        float h0 = hin[n0 * 32 + lane];
        float h1 = hin[n1 * 32 + lane];
        float bF = blF[lane], bR = blR[lane];
        float aF0 = bF, aR0 = bR, aF1 = bF, aR1 = bR;
        #pragma unroll
        for (int k = 0; k < 32; ++k) {
            float f0 = __shfl(sF0, k, 32);
            float r0 = __shfl(sR0, k, 32);
            float f1 = __shfl(sF1, k, 32);
            float r1 = __shfl(sR1, k, 32);
            float hk0 = __shfl(h0, k, 32);
            float hk1 = __shfl(h1, k, 32);
            float wlf = WLF[k][lane], wrf = WRF[k][lane];
            float wlr = WLR[k][lane], wrr = WRR[k][lane];
            aF0 = fmaf(f0, wlf, aF0); aF0 = fmaf(hk0, wrf, aF0);
            aR0 = fmaf(r0, wlr, aR0); aR0 = fmaf(hk0, wrr, aR0);
            aF1 = fmaf(f1, wlf, aF1); aF1 = fmaf(hk1, wrf, aF1);
            aR1 = fmaf(r1, wlr, aR1); aR1 = fmaf(hk1, wrr, aR1);
        }
        hout[n0 * 32 + lane] = fmaxf(aF0, 0.f) + fmaxf(aR0, 0.f);
        hout[n1 * 32 + lane] = fmaxf(aF1, 0.f) + fmaxf(aR1, 0.f);
    }
}

__global__ void k_pair(const float* __restrict__ h, const int* __restrict__ pos1,
                       float* __restrict__ hp, int total) {
    int idx = blockIdx.x * blockDim.x + threadIdx.x;
    int stride = gridDim.x * blockDim.x;
    for (; idx < total; idx += stride) {
        int r = idx >> 5, k = idx & 31;
        int a = pos1[2 * r], b = pos1[2 * r + 1];
        hp[idx] = h[a * 32 + k] * h[b * 32 + k];
    }
}

__global__ void k_final(const float* __restrict__ h, const int* __restrict__ pos2,
                        const float* __restrict__ pw, const float* __restrict__ pb,
                        float* __restrict__ out, int m2) {
    int tid  = threadIdx.x;
    int lane = tid & 31;
    int i    = blockIdx.x * 8 + (tid >> 5);
    if (i >= m2) return;
    int p0 = pos2[2 * i], p1 = pos2[2 * i + 1];
    float v = h[p0 * 32 + lane] * h[p1 * 32 + lane] * pw[lane];
    #pragma unroll
    for (int o = 16; o > 0; o >>= 1) v += __shfl_xor(v, o, 32);
    if (lane == 0) out[i] = v + pb[0];
}

// ---------------- launch ----------------

extern "C" void kernel_launch(void* const* d_in, const int* in_sizes, int n_in,
                              void* d_out, int out_size, void* d_ws, size_t ws_size,
                              hipStream_t stream) {
    const int*   x      = (const int*)d_in[0];
    const int*   edge1  = (const int*)d_in[2];
    const int*   edge2  = (const int*)d_in[3];
    const int*   edge2r = (const int*)d_in[4];
    const int*   pos1   = (const int*)d_in[5];
    const int*   pos2   = (const int*)d_in[6];
    const float* emb    = (const float*)d_in[7];
    const float* gw     = (const float*)d_in[8];
    const float* gb     = (const float*)d_in[9];
    const float* gms    = (const float*)d_in[10];
    const float* c1wl   = (const float*)d_in[11];
    const float* c1bl   = (const float*)d_in[12];
    const float* c1wr   = (const float*)d_in[13];
    const float* c2wl   = (const float*)d_in[14];
    const float* c2bl   = (const float*)d_in[15];
    const float* c2wr   = (const float*)d_in[16];
    const float* c2rwl  = (const float*)d_in[17];
    const float* c2rbl  = (const float*)d_in[18];
    const float* c2rwr  = (const float*)d_in[19];
    const float* pw     = (const float*)d_in[20];
    const float* pb     = (const float*)d_in[21];
    float* out = (float*)d_out;

    char* ws = (char*)d_ws;
    float* hA    = (float*)(ws + OFF_HA);
    float* hB    = (float*)(ws + OFF_HB);
    int*   csrA  = (int*)(ws + OFF_CSRA);
    int*   csrB  = (int*)(ws + OFF_CSRB);
    int*   off1  = (int*)(ws + OFF_OFF1);
    int*   off2  = (int*)(ws + OFF_OFF2);
    int*   off2r = (int*)(ws + OFF_OFF2R);
    int*   cur   = (int*)(ws + OFF_CUR);
    int*   cur2r = (int*)(ws + OFF_CUR2R);
    int*   bsumA = (int*)(ws + OFF_BSUMA);
    int*   bsumB = (int*)(ws + OFF_BSUMB);
    int*   bsumC = (int*)(ws + OFF_BSUMC);
    float* stats = (float*)(ws + OFF_STATS);
    float* aff   = (float*)(ws + OFF_AFF);

    hipMemsetAsync(stats, 0, 256, stream);
    hipMemsetAsync(off1, 0, (NN + 1) * sizeof(int), stream);
    hipMemsetAsync(off2, 0, (N2N + 1) * sizeof(int), stream);
    hipMemsetAsync(off2r, 0, (N2N + 1) * sizeof(int), stream);

    // embedding + GraphNorm
    k_embed_stats<<<1024, 256, 0, stream>>>(x, emb, hA, stats, NN);
    k_affine<<<1, 64, 0, stream>>>(stats, gw, gb, gms, aff, NN);
    k_apply_affine<<<2048, 256, 0, stream>>>(hA, aff, NN * 32);

    // CSR for edge1 (into csrA)
    int nb1 = (NN + SCAN_CHUNK - 1) / SCAN_CHUNK;
    k_count<<<2048, 256, 0, stream>>>(edge1 + E1N, off1, E1N);
    k_scan_partial<<<nb1, 256, 0, stream>>>(off1, bsumA, NN);
    k_scan_bsum2<<<1, 128, 0, stream>>>(bsumA, nb1, bsumA, 0);
    k_scan_final<<<nb1, 256, 0, stream>>>(off1, cur, bsumA, NN);
    k_fill<<<2048, 256, 0, stream>>>(edge1, edge1 + E1N, cur, csrA, E1N);

    // conv1: hA -> hB -> hA
    k_sage<<<2048, 256, 0, stream>>>(hA, hB, csrA, off1, c1wl, c1bl, c1wr, NN);
    k_sage<<<2048, 256, 0, stream>>>(hB, hA, csrA, off1,
                                     c1wl + 1024, c1bl + 32, c1wr + 1024, NN);

    // pair features: hA (N rows) -> hB (N2 rows)
    k_pair<<<2048, 256, 0, stream>>>(hA, pos1, hB, N2N * 32);

    // CSR for edge2 (into csrA) and edge2_r (into csrB), fused builds
    int nb2 = (N2N + SCAN_CHUNK - 1) / SCAN_CHUNK;
    k_count2<<<4096, 256, 0, stream>>>(edge2 + E2N, off2, edge2r + E2N, off2r, E2N);
    k_scan_partial2<<<2 * nb2, 256, 0, stream>>>(off2, bsumB, off2r, bsumC, N2N, nb2);
    k_scan_bsum2<<<2, 128, 0, stream>>>(bsumB, nb2, bsumC, nb2);
    k_scan_final2<<<2 * nb2, 256, 0, stream>>>(off2, cur, bsumB, off2r, cur2r, bsumC, N2N, nb2);
    k_fill2<<<4096, 256, 0, stream>>>(edge2, edge2 + E2N, cur, csrA,
                                      edge2r, edge2r + E2N, cur2r, csrB, E2N);

    // conv2: hB -> hA -> hB  (fused forward+reverse each layer)
    k_sage2<<<2048, 256, 0, stream>>>(hB, hA, csrA, off2, csrB, off2r,
        c2wl, c2bl, c2wr, c2rwl, c2rbl, c2rwr, N2N);
    k_sage2<<<2048, 256, 0, stream>>>(hA, hB, csrA, off2, csrB, off2r,
        c2wl + 1024, c2bl + 32, c2wr + 1024, c2rwl + 1024, c2rbl + 32, c2rwr + 1024, N2N);

    // head: gather pos2, even*odd, dot with pred_w
    k_final<<<(MN / 2) / 8, 256, 0, stream>>>(hB, pos2, pw, pb, out, MN / 2);
}